// Round 3
// baseline (348.232 us; speedup 1.0000x reference)
//
#include <hip/hip_runtime.h>
#include <hip/hip_bf16.h>

// Problem constants
constexpr int Bb = 8, Nn = 4096, Ss = 1024;
constexpr int D1 = 128, D2 = 256, KIN = 384, OC = 256;
constexpr int L = Bb * Nn;             // 32768 rows
constexpr float BN_EPS = 1e-5f;

typedef __attribute__((ext_vector_type(4))) float floatx4;
typedef __attribute__((ext_vector_type(8))) __bf16 bf16x8;

#define DEV __device__ __forceinline__

DEV float bf2f(unsigned short u) {
    union { unsigned int i; float f; } v; v.i = ((unsigned int)u) << 16; return v.f;
}
DEV unsigned short f2bf(float f) {
    union { float f; unsigned int i; } v; v.f = f;
    unsigned int x = v.i;
    return (unsigned short)((x + 0x7FFFu + ((x >> 16) & 1u)) >> 16);  // RNE
}
DEV float gelu_f(float x) { return 0.5f * x * (1.0f + erff(x * 0.70710678118654752f)); }

// ---------------- dtype probe: low ushort of f32 words is mantissa junk ----------------
__global__ void k_probe(const unsigned int* __restrict__ w, int* __restrict__ flag) {
    if (threadIdx.x == 0 && blockIdx.x == 0) {
        int sane = 0;
        for (int i = 0; i < 64; ++i) {
            unsigned int lo = w[i] & 0xFFFFu;
            int e = (int)((lo >> 7) & 0xFF);
            if (e >= 100 && e <= 144) ++sane;
        }
        *flag = (sane >= 48) ? 0 : 1;   // 0 = bf16 inputs, 1 = f32 inputs
    }
}

// ---------------- zero stats accumulators ----------------
__global__ void k_zero(float* p) {
    int i = blockIdx.x * 256 + threadIdx.x;
    if (i < 6 * 256) p[i] = 0.0f;
}

// ---------------- weights -> bf16 (copy or convert) ----------------
__global__ void k_prep_w(const void* __restrict__ src, unsigned short* __restrict__ dst,
                         int n, const int* __restrict__ dflag) {
    int i = blockIdx.x * 256 + threadIdx.x;
    if (i >= n) return;
    if (*dflag) dst[i] = f2bf(((const float*)src)[i]);
    else        dst[i] = ((const unsigned short*)src)[i];
}

// ---------------- 3-NN search + weights ----------------
// grid: 128 blocks (8 batches x 16 chunks of 256 points), 256 threads
__global__ __launch_bounds__(256) void k_nn(const void* __restrict__ xyz1_,
                                            const void* __restrict__ xyz2_,
                                            const int* __restrict__ dflag,
                                            int* __restrict__ nn_idx, float* __restrict__ nn_w) {
    __shared__ alignas(16) float s4[Ss * 4];  // x,y,z,|p|^2 per source point
    int b = blockIdx.x >> 4;
    int chunk = blockIdx.x & 15;
    int tid = threadIdx.x;
    bool isf = (*dflag != 0);

    if (isf) {
        const float* p2 = (const float*)xyz2_ + (size_t)b * Ss * 3;
        for (int i = tid; i < Ss * 3; i += 256) {
            int s = i / 3, k = i - s * 3;
            s4[s * 4 + k] = p2[i];
        }
    } else {
        const unsigned short* p2 = (const unsigned short*)xyz2_ + (size_t)b * Ss * 3;
        for (int i = tid; i < Ss * 3; i += 256) {
            int s = i / 3, k = i - s * 3;
            s4[s * 4 + k] = bf2f(p2[i]);
        }
    }
    __syncthreads();
    for (int s = tid; s < Ss; s += 256) {
        float x = s4[s * 4], y = s4[s * 4 + 1], z = s4[s * 4 + 2];
        s4[s * 4 + 3] = x * x + y * y + z * z;
    }
    __syncthreads();

    int n = chunk * 256 + tid;
    int bn = b * Nn + n;
    float x1, y1, z1;
    if (isf) {
        const float* p1 = (const float*)xyz1_ + (size_t)bn * 3;
        x1 = p1[0]; y1 = p1[1]; z1 = p1[2];
    } else {
        const unsigned short* p1 = (const unsigned short*)xyz1_ + (size_t)bn * 3;
        x1 = bf2f(p1[0]); y1 = bf2f(p1[1]); z1 = bf2f(p1[2]);
    }
    float n1 = x1 * x1 + y1 * y1 + z1 * z1;

    float d0 = 3.4e38f, d1 = 3.4e38f, d2 = 3.4e38f;
    int i0 = 0, i1 = 0, i2 = 0;
#pragma unroll 4
    for (int s = 0; s < Ss; ++s) {
        float4 q = *(const float4*)&s4[s * 4];
        float d = n1 + q.w - 2.0f * (x1 * q.x + y1 * q.y + z1 * q.z);
        bool c2 = d < d2, c1 = d < d1, c0 = d < d0;
        // branchless 3-deep insertion; strict < keeps earlier index on ties (top_k tie rule)
        d2 = c1 ? d1 : (c2 ? d : d2); i2 = c1 ? i1 : (c2 ? s : i2);
        d1 = c0 ? d0 : (c1 ? d : d1); i1 = c0 ? i0 : (c1 ? s : i1);
        d0 = c0 ? d  : d0;            i0 = c0 ? s  : i0;
    }
    float r0 = 1.0f / (d0 + 1e-8f), r1 = 1.0f / (d1 + 1e-8f), r2 = 1.0f / (d2 + 1e-8f);
    float rs = 1.0f / (r0 + r1 + r2);
    nn_idx[bn * 3 + 0] = i0; nn_idx[bn * 3 + 1] = i1; nn_idx[bn * 3 + 2] = i2;
    nn_w[bn * 3 + 0] = r0 * rs; nn_w[bn * 3 + 1] = r1 * rs; nn_w[bn * 3 + 2] = r2 * rs;
}

// ---------------- build X = concat(points1, interp) as (L, 384) bf16 ----------------
// grid: 8192 blocks x 256 threads; 4 points/block, 64 lanes per point
__global__ __launch_bounds__(256) void k_build_x(const void* __restrict__ points1_,
                                                 const void* __restrict__ points2_,
                                                 const int* __restrict__ dflag,
                                                 const int* __restrict__ nn_idx,
                                                 const float* __restrict__ nn_w,
                                                 unsigned short* __restrict__ X) {
    int tid = threadIdx.x;
    int pt = blockIdx.x * 4 + (tid >> 6);
    int lane = tid & 63;
    int b = pt >> 12;  // / Nn
    bool isf = (*dflag != 0);

    int i0 = nn_idx[pt * 3], i1 = nn_idx[pt * 3 + 1], i2 = nn_idx[pt * 3 + 2];
    float w0 = nn_w[pt * 3], w1 = nn_w[pt * 3 + 1], w2 = nn_w[pt * 3 + 2];
    int c = lane * 4;  // 4 interp channels / lane

    if (isf) {
        const float* p1 = (const float*)points1_ + (size_t)pt * D1;
        float2 v = *(const float2*)(p1 + lane * 2);
        unsigned int packed = (unsigned int)f2bf(v.x) | ((unsigned int)f2bf(v.y) << 16);
        ((unsigned int*)(X + (size_t)pt * KIN))[lane] = packed;

        const float* base = (const float*)points2_;
        const float* r0 = base + ((size_t)(b * Ss + i0)) * D2 + c;
        const float* r1 = base + ((size_t)(b * Ss + i1)) * D2 + c;
        const float* r2 = base + ((size_t)(b * Ss + i2)) * D2 + c;
        float4 a0 = *(const float4*)r0;
        float4 a1 = *(const float4*)r1;
        float4 a2 = *(const float4*)r2;
        uint2 out;
        unsigned short* uo = (unsigned short*)&out;
        uo[0] = f2bf(w0 * a0.x + w1 * a1.x + w2 * a2.x);
        uo[1] = f2bf(w0 * a0.y + w1 * a1.y + w2 * a2.y);
        uo[2] = f2bf(w0 * a0.z + w1 * a1.z + w2 * a2.z);
        uo[3] = f2bf(w0 * a0.w + w1 * a1.w + w2 * a2.w);
        *(uint2*)(X + (size_t)pt * KIN + D1 + c) = out;
    } else {
        const unsigned short* p1 = (const unsigned short*)points1_;
        ((unsigned int*)(X + (size_t)pt * KIN))[lane] =
            ((const unsigned int*)(p1 + (size_t)pt * D1))[lane];

        const unsigned short* base = (const unsigned short*)points2_;
        const unsigned short* r0 = base + ((size_t)(b * Ss + i0)) * D2 + c;
        const unsigned short* r1 = base + ((size_t)(b * Ss + i1)) * D2 + c;
        const unsigned short* r2 = base + ((size_t)(b * Ss + i2)) * D2 + c;
        uint2 v0 = *(const uint2*)r0;
        uint2 v1 = *(const uint2*)r1;
        uint2 v2 = *(const uint2*)r2;
        const unsigned short* u0 = (const unsigned short*)&v0;
        const unsigned short* u1 = (const unsigned short*)&v1;
        const unsigned short* u2 = (const unsigned short*)&v2;
        uint2 out;
        unsigned short* uo = (unsigned short*)&out;
#pragma unroll
        for (int j = 0; j < 4; ++j)
            uo[j] = f2bf(w0 * bf2f(u0[j]) + w1 * bf2f(u1[j]) + w2 * bf2f(u2[j]));
        *(uint2*)(X + (size_t)pt * KIN + D1 + c) = out;
    }
}

// ---------------- GEMM: C[l][o] = sum_c act(A[l][c]) * W[o][c], + channel stats ----------------
// A: (L,K) bf16 row-major; W: (256,K) bf16 row-major; Out: (L,256) bf16.
// ACT: apply gelu(cA[c]*x + cC[c]) to A during staging.
// grid: (L/128, 2); 256 threads = 4 waves (2x2), each wave 64x64 via 4x4 16x16x32 MFMA tiles.
template <int K, int ACT>
__global__ __launch_bounds__(256) void k_gemm(const unsigned short* __restrict__ A,
                                              const unsigned short* __restrict__ W,
                                              unsigned short* __restrict__ Out,
                                              float* __restrict__ S1, float* __restrict__ S2,
                                              const float* __restrict__ cA,
                                              const float* __restrict__ cC) {
    __shared__ alignas(16) unsigned short As[128 * 64];
    __shared__ alignas(16) unsigned short Bs[128 * 64];
    __shared__ float sS1[128], sS2[128];

    int tid = threadIdx.x;
    int l0 = blockIdx.x * 128;
    int o0 = blockIdx.y * 128;
    int wave = tid >> 6, lane = tid & 63, quad = lane >> 4, lr = lane & 15;
    int wm = wave >> 1, wn = wave & 1;

    floatx4 zero4 = {0.f, 0.f, 0.f, 0.f};
    floatx4 acc[4][4];
#pragma unroll
    for (int mi = 0; mi < 4; ++mi)
#pragma unroll
        for (int ni = 0; ni < 4; ++ni) acc[mi][ni] = zero4;

    constexpr int KC = K / 64;
    for (int kc = 0; kc < KC; ++kc) {
        __syncthreads();
        // stage A and B tiles (128 x 64 bf16 each); XOR-swizzled 16B chunks
#pragma unroll
        for (int it = 0; it < 4; ++it) {
            int idx = it * 256 + tid;
            int row = idx >> 3, c8 = idx & 7;
            union { uint4 v; unsigned short u[8]; } va;
            va.v = *(const uint4*)(A + (size_t)(l0 + row) * K + kc * 64 + c8 * 8);
            if (ACT) {
                int kbase = kc * 64 + c8 * 8;
#pragma unroll
                for (int j = 0; j < 8; ++j) {
                    float f = bf2f(va.u[j]);
                    va.u[j] = f2bf(gelu_f(cA[kbase + j] * f + cC[kbase + j]));
                }
            }
            *(uint4*)&As[row * 64 + ((c8 ^ (row & 7)) << 3)] = va.v;

            uint4 vb = *(const uint4*)(W + (size_t)(o0 + row) * K + kc * 64 + c8 * 8);
            *(uint4*)&Bs[row * 64 + ((c8 ^ (row & 7)) << 3)] = vb;
        }
        __syncthreads();
#pragma unroll
        for (int ks8 = 0; ks8 < 2; ++ks8) {
            bf16x8 af[4], bfr[4];
#pragma unroll
            for (int mi = 0; mi < 4; ++mi) {
                int ra = wm * 64 + mi * 16 + lr;
                af[mi] = *(const bf16x8*)&As[ra * 64 + ((((ks8 << 2) + quad) ^ (ra & 7)) << 3)];
            }
#pragma unroll
            for (int ni = 0; ni < 4; ++ni) {
                int rb = wn * 64 + ni * 16 + lr;
                bfr[ni] = *(const bf16x8*)&Bs[rb * 64 + ((((ks8 << 2) + quad) ^ (rb & 7)) << 3)];
            }
#pragma unroll
            for (int mi = 0; mi < 4; ++mi)
#pragma unroll
                for (int ni = 0; ni < 4; ++ni)
                    acc[mi][ni] = __builtin_amdgcn_mfma_f32_16x16x32_bf16(af[mi], bfr[ni], acc[mi][ni], 0, 0, 0);
        }
    }

    // epilogue: write bf16 + per-channel partial sums (for BN stats)
    float p1[4] = {0, 0, 0, 0}, p2[4] = {0, 0, 0, 0};
#pragma unroll
    for (int mi = 0; mi < 4; ++mi) {
#pragma unroll
        for (int ni = 0; ni < 4; ++ni) {
#pragma unroll
            for (int r = 0; r < 4; ++r) {
                float v = acc[mi][ni][r];
                int row = l0 + wm * 64 + mi * 16 + quad * 4 + r;
                int col = o0 + wn * 64 + ni * 16 + lr;
                Out[(size_t)row * OC + col] = f2bf(v);
                p1[ni] += v;
                p2[ni] += v * v;
            }
        }
    }
    if (tid < 128) { sS1[tid] = 0.f; sS2[tid] = 0.f; }
    __syncthreads();
#pragma unroll
    for (int ni = 0; ni < 4; ++ni) {
        atomicAdd(&sS1[wn * 64 + ni * 16 + lr], p1[ni]);
        atomicAdd(&sS2[wn * 64 + ni * 16 + lr], p2[ni]);
    }
    __syncthreads();
    if (tid < 128) {
        atomicAdd(&S1[o0 + tid], sS1[tid]);
        atomicAdd(&S2[o0 + tid], sS2[tid]);
    }
}

// ---------------- BN coefficient finalize: a = g*rsqrt(var+eps), c = bt - mean*a ----------------
__global__ void k_finalize(const float* __restrict__ S1, const float* __restrict__ S2,
                           const void* __restrict__ g_, const void* __restrict__ bt_,
                           const int* __restrict__ dflag,
                           float* __restrict__ cA, float* __restrict__ cC) {
    int o = threadIdx.x;
    float m = S1[o] * (1.0f / (float)L);
    float var = S2[o] * (1.0f / (float)L) - m * m;
    float g, bt;
    if (*dflag) { g = ((const float*)g_)[o]; bt = ((const float*)bt_)[o]; }
    else { g = bf2f(((const unsigned short*)g_)[o]); bt = bf2f(((const unsigned short*)bt_)[o]); }
    float a = g * rsqrtf(var + BN_EPS);
    cA[o] = a;
    cC[o] = bt - m * a;
}

// ---------------- final: out = gelu( bn2(t2) + gelu(bn0(t0)) ); out dtype per dflag ----------------
__global__ __launch_bounds__(256) void k_final(const unsigned short* __restrict__ t0,
                                               const unsigned short* __restrict__ t2,
                                               const float* __restrict__ cA0, const float* __restrict__ cC0,
                                               const float* __restrict__ cA2, const float* __restrict__ cC2,
                                               const int* __restrict__ dflag,
                                               void* __restrict__ out_) {
    int idx = (blockIdx.x * 256 + threadIdx.x) * 8;
    int col = idx & (OC - 1);
    union { uint4 v; unsigned short u[8]; } v0, v2;
    v0.v = *(const uint4*)(t0 + idx);
    v2.v = *(const uint4*)(t2 + idx);
    float r[8];
#pragma unroll
    for (int j = 0; j < 8; ++j) {
        float x = gelu_f(cA0[col + j] * bf2f(v0.u[j]) + cC0[col + j]);
        float y = cA2[col + j] * bf2f(v2.u[j]) + cC2[col + j];
        r[j] = gelu_f(x + y);
    }
    if (*dflag) {
        float* o = (float*)out_ + idx;
        float4 lo = {r[0], r[1], r[2], r[3]};
        float4 hi = {r[4], r[5], r[6], r[7]};
        *(float4*)o = lo;
        *(float4*)(o + 4) = hi;
    } else {
        union { uint4 v; unsigned short u[8]; } vo;
#pragma unroll
        for (int j = 0; j < 8; ++j) vo.u[j] = f2bf(r[j]);
        *(uint4*)((unsigned short*)out_ + idx) = vo.v;
    }
}

extern "C" void kernel_launch(void* const* d_in, const int* in_sizes, int n_in,
                              void* d_out, int out_size, void* d_ws, size_t ws_size,
                              hipStream_t stream) {
    const void* xyz1    = d_in[0];
    const void* xyz2    = d_in[1];
    const void* points1 = d_in[2];
    const void* points2 = d_in[3];
    const void* W_fuse  = d_in[4];
    const void* g_fuse  = d_in[6];
    const void* bt_fuse = d_in[7];
    const void* W1      = d_in[8];
    const void* g1      = d_in[10];
    const void* bt1     = d_in[11];
    const void* W2      = d_in[12];
    const void* g2      = d_in[14];
    const void* bt2     = d_in[15];

    char* ws = (char*)d_ws;
    // ws layout: X (24MB, reused as t2) | t0 (16MB) | nn_idx | nn_w | stats+flag | Wbf x3.
    // t1 lives in d_out (scratch until k_final overwrites it).
    unsigned short* X  = (unsigned short*)ws;
    unsigned short* t0 = (unsigned short*)(ws + 25165824);
    unsigned short* t1 = (unsigned short*)d_out;   // 16.8 MB bf16 scratch; d_out >= 16.8 MB either dtype
    unsigned short* t2 = X;                        // X dead after GEMM1
    int*   nn_idx = (int*)(ws + 41943040);
    float* nn_w   = (float*)(ws + 42336256);
    float* stats  = (float*)(ws + 42729472);
    int*   dflag  = (int*)(ws + 42729472 + 3072 * 4);
    unsigned short* Wf_bf = (unsigned short*)(ws + 42745856);
    unsigned short* W1_bf = Wf_bf + 256 * KIN;
    unsigned short* W2_bf = W1_bf + 256 * OC;

    float *S1_0 = stats,        *S2_0 = stats + 256;
    float *S1_1 = stats + 512,  *S2_1 = stats + 768;
    float *S1_2 = stats + 1024, *S2_2 = stats + 1280;
    float *cA0 = stats + 1536, *cC0 = stats + 1792;
    float *cA1 = stats + 2048, *cC1 = stats + 2304;
    float *cA2 = stats + 2560, *cC2 = stats + 2816;

    k_probe<<<1, 64, 0, stream>>>((const unsigned int*)xyz1, dflag);
    k_zero<<<6, 256, 0, stream>>>(stats);
    k_prep_w<<<(256 * KIN + 255) / 256, 256, 0, stream>>>(W_fuse, Wf_bf, 256 * KIN, dflag);
    k_prep_w<<<(256 * OC + 255) / 256, 256, 0, stream>>>(W1, W1_bf, 256 * OC, dflag);
    k_prep_w<<<(256 * OC + 255) / 256, 256, 0, stream>>>(W2, W2_bf, 256 * OC, dflag);
    k_nn<<<128, 256, 0, stream>>>(xyz1, xyz2, dflag, nn_idx, nn_w);
    k_build_x<<<L / 4, 256, 0, stream>>>(points1, points2, dflag, nn_idx, nn_w, X);

    dim3 ggrid(L / 128, 2);
    k_gemm<KIN, 0><<<ggrid, 256, 0, stream>>>(X, Wf_bf, t0, S1_0, S2_0, nullptr, nullptr);
    k_finalize<<<1, 256, 0, stream>>>(S1_0, S2_0, g_fuse, bt_fuse, dflag, cA0, cC0);
    k_gemm<OC, 1><<<ggrid, 256, 0, stream>>>(t0, W1_bf, t1, S1_1, S2_1, cA0, cC0);
    k_finalize<<<1, 256, 0, stream>>>(S1_1, S2_1, g1, bt1, dflag, cA1, cC1);
    k_gemm<OC, 1><<<ggrid, 256, 0, stream>>>(t1, W2_bf, t2, S1_2, S2_2, cA1, cC1);
    k_finalize<<<1, 256, 0, stream>>>(S1_2, S2_2, g2, bt2, dflag, cA2, cC2);
    k_final<<<L * OC / (256 * 8), 256, 0, stream>>>(t0, t2, cA0, cC0, cA2, cC2, dflag, d_out);
}

// Round 4
// 279.057 us; speedup vs baseline: 1.2479x; 1.2479x over previous
//
#include <hip/hip_runtime.h>
#include <hip/hip_bf16.h>

// Problem constants
constexpr int Bb = 8, Nn = 4096, Ss = 1024;
constexpr int D1 = 128, D2 = 256, KIN = 384, OC = 256;
constexpr int L = Bb * Nn;             // 32768 rows
constexpr float BN_EPS = 1e-5f;

typedef __attribute__((ext_vector_type(4))) float floatx4;
typedef __attribute__((ext_vector_type(8))) __bf16 bf16x8;

#define DEV __device__ __forceinline__

DEV float bf2f(unsigned short u) {
    union { unsigned int i; float f; } v; v.i = ((unsigned int)u) << 16; return v.f;
}
DEV unsigned short f2bf(float f) {
    union { float f; unsigned int i; } v; v.f = f;
    unsigned int x = v.i;
    return (unsigned short)((x + 0x7FFFu + ((x >> 16) & 1u)) >> 16);  // RNE
}
// Fast tanh-form gelu: x*sigmoid(2u), u = sqrt(2/pi)*(x+0.044715x^3).
// ~7 VALU ops (v_exp_f32 + v_rcp_f32), no branches; |err vs exact| < 4e-3
// (threshold is 0.1675; bf16 rounding already contributes ~0.06).
DEV float gelu_f(float x) {
    float u = x * (0.7978845608f + 0.0356774081f * x * x);
    float t = __expf(-2.0f * u);
    return x * __builtin_amdgcn_rcpf(1.0f + t);
}

// ---------------- dtype probe: low ushort of f32 words is mantissa junk ----------------
__global__ void k_probe(const unsigned int* __restrict__ w, int* __restrict__ flag) {
    if (threadIdx.x == 0 && blockIdx.x == 0) {
        int sane = 0;
        for (int i = 0; i < 64; ++i) {
            unsigned int lo = w[i] & 0xFFFFu;
            int e = (int)((lo >> 7) & 0xFF);
            if (e >= 100 && e <= 144) ++sane;
        }
        *flag = (sane >= 48) ? 0 : 1;   // 0 = bf16 inputs, 1 = f32 inputs
    }
}

// ---------------- zero stats accumulators ----------------
__global__ void k_zero(float* p) {
    int i = blockIdx.x * 256 + threadIdx.x;
    if (i < 6 * 256) p[i] = 0.0f;
}

// ---------------- weights -> bf16 (copy or convert) ----------------
__global__ void k_prep_w(const void* __restrict__ src, unsigned short* __restrict__ dst,
                         int n, const int* __restrict__ dflag) {
    int i = blockIdx.x * 256 + threadIdx.x;
    if (i >= n) return;
    if (*dflag) dst[i] = f2bf(((const float*)src)[i]);
    else        dst[i] = ((const unsigned short*)src)[i];
}

// ---------------- 3-NN search + weights ----------------
// grid: 128 blocks (8 batches x 16 chunks of 256 points), 256 threads
__global__ __launch_bounds__(256) void k_nn(const void* __restrict__ xyz1_,
                                            const void* __restrict__ xyz2_,
                                            const int* __restrict__ dflag,
                                            int* __restrict__ nn_idx, float* __restrict__ nn_w) {
    __shared__ alignas(16) float s4[Ss * 4];  // x,y,z,|p|^2 per source point
    int b = blockIdx.x >> 4;
    int chunk = blockIdx.x & 15;
    int tid = threadIdx.x;
    bool isf = (*dflag != 0);

    if (isf) {
        const float* p2 = (const float*)xyz2_ + (size_t)b * Ss * 3;
        for (int i = tid; i < Ss * 3; i += 256) {
            int s = i / 3, k = i - s * 3;
            s4[s * 4 + k] = p2[i];
        }
    } else {
        const unsigned short* p2 = (const unsigned short*)xyz2_ + (size_t)b * Ss * 3;
        for (int i = tid; i < Ss * 3; i += 256) {
            int s = i / 3, k = i - s * 3;
            s4[s * 4 + k] = bf2f(p2[i]);
        }
    }
    __syncthreads();
    for (int s = tid; s < Ss; s += 256) {
        float x = s4[s * 4], y = s4[s * 4 + 1], z = s4[s * 4 + 2];
        s4[s * 4 + 3] = x * x + y * y + z * z;
    }
    __syncthreads();

    int n = chunk * 256 + tid;
    int bn = b * Nn + n;
    float x1, y1, z1;
    if (isf) {
        const float* p1 = (const float*)xyz1_ + (size_t)bn * 3;
        x1 = p1[0]; y1 = p1[1]; z1 = p1[2];
    } else {
        const unsigned short* p1 = (const unsigned short*)xyz1_ + (size_t)bn * 3;
        x1 = bf2f(p1[0]); y1 = bf2f(p1[1]); z1 = bf2f(p1[2]);
    }
    float n1 = x1 * x1 + y1 * y1 + z1 * z1;

    float d0 = 3.4e38f, d1 = 3.4e38f, d2 = 3.4e38f;
    int i0 = 0, i1 = 0, i2 = 0;
#pragma unroll 4
    for (int s = 0; s < Ss; ++s) {
        float4 q = *(const float4*)&s4[s * 4];
        float d = n1 + q.w - 2.0f * (x1 * q.x + y1 * q.y + z1 * q.z);
        bool c2 = d < d2, c1 = d < d1, c0 = d < d0;
        // branchless 3-deep insertion; strict < keeps earlier index on ties (top_k tie rule)
        d2 = c1 ? d1 : (c2 ? d : d2); i2 = c1 ? i1 : (c2 ? s : i2);
        d1 = c0 ? d0 : (c1 ? d : d1); i1 = c0 ? i0 : (c1 ? s : i1);
        d0 = c0 ? d  : d0;            i0 = c0 ? s  : i0;
    }
    float r0 = 1.0f / (d0 + 1e-8f), r1 = 1.0f / (d1 + 1e-8f), r2 = 1.0f / (d2 + 1e-8f);
    float rs = 1.0f / (r0 + r1 + r2);
    nn_idx[bn * 3 + 0] = i0; nn_idx[bn * 3 + 1] = i1; nn_idx[bn * 3 + 2] = i2;
    nn_w[bn * 3 + 0] = r0 * rs; nn_w[bn * 3 + 1] = r1 * rs; nn_w[bn * 3 + 2] = r2 * rs;
}

// ---------------- build X = concat(points1, interp) as (L, 384) bf16 ----------------
// grid: 8192 blocks x 256 threads; 4 points/block, 64 lanes per point
__global__ __launch_bounds__(256) void k_build_x(const void* __restrict__ points1_,
                                                 const void* __restrict__ points2_,
                                                 const int* __restrict__ dflag,
                                                 const int* __restrict__ nn_idx,
                                                 const float* __restrict__ nn_w,
                                                 unsigned short* __restrict__ X) {
    int tid = threadIdx.x;
    int pt = blockIdx.x * 4 + (tid >> 6);
    int lane = tid & 63;
    int b = pt >> 12;  // / Nn
    bool isf = (*dflag != 0);

    int i0 = nn_idx[pt * 3], i1 = nn_idx[pt * 3 + 1], i2 = nn_idx[pt * 3 + 2];
    float w0 = nn_w[pt * 3], w1 = nn_w[pt * 3 + 1], w2 = nn_w[pt * 3 + 2];
    int c = lane * 4;  // 4 interp channels / lane

    if (isf) {
        const float* p1 = (const float*)points1_ + (size_t)pt * D1;
        float2 v = *(const float2*)(p1 + lane * 2);
        unsigned int packed = (unsigned int)f2bf(v.x) | ((unsigned int)f2bf(v.y) << 16);
        ((unsigned int*)(X + (size_t)pt * KIN))[lane] = packed;

        const float* base = (const float*)points2_;
        const float* r0 = base + ((size_t)(b * Ss + i0)) * D2 + c;
        const float* r1 = base + ((size_t)(b * Ss + i1)) * D2 + c;
        const float* r2 = base + ((size_t)(b * Ss + i2)) * D2 + c;
        float4 a0 = *(const float4*)r0;
        float4 a1 = *(const float4*)r1;
        float4 a2 = *(const float4*)r2;
        uint2 out;
        unsigned short* uo = (unsigned short*)&out;
        uo[0] = f2bf(w0 * a0.x + w1 * a1.x + w2 * a2.x);
        uo[1] = f2bf(w0 * a0.y + w1 * a1.y + w2 * a2.y);
        uo[2] = f2bf(w0 * a0.z + w1 * a1.z + w2 * a2.z);
        uo[3] = f2bf(w0 * a0.w + w1 * a1.w + w2 * a2.w);
        *(uint2*)(X + (size_t)pt * KIN + D1 + c) = out;
    } else {
        const unsigned short* p1 = (const unsigned short*)points1_;
        ((unsigned int*)(X + (size_t)pt * KIN))[lane] =
            ((const unsigned int*)(p1 + (size_t)pt * D1))[lane];

        const unsigned short* base = (const unsigned short*)points2_;
        const unsigned short* r0 = base + ((size_t)(b * Ss + i0)) * D2 + c;
        const unsigned short* r1 = base + ((size_t)(b * Ss + i1)) * D2 + c;
        const unsigned short* r2 = base + ((size_t)(b * Ss + i2)) * D2 + c;
        uint2 v0 = *(const uint2*)r0;
        uint2 v1 = *(const uint2*)r1;
        uint2 v2 = *(const uint2*)r2;
        const unsigned short* u0 = (const unsigned short*)&v0;
        const unsigned short* u1 = (const unsigned short*)&v1;
        const unsigned short* u2 = (const unsigned short*)&v2;
        uint2 out;
        unsigned short* uo = (unsigned short*)&out;
#pragma unroll
        for (int j = 0; j < 4; ++j)
            uo[j] = f2bf(w0 * bf2f(u0[j]) + w1 * bf2f(u1[j]) + w2 * bf2f(u2[j]));
        *(uint2*)(X + (size_t)pt * KIN + D1 + c) = out;
    }
}

// ---------------- GEMM: C[l][o] = sum_c act(A[l][c]) * W[o][c], + channel stats ----------------
// A: (L,K) bf16 row-major; W: (256,K) bf16 row-major; Out: (L,256) bf16.
// ACT: apply gelu(cA[c]*x + cC[c]) to A during staging.
// grid: (L/128, 2); 256 threads = 4 waves (2x2), each wave 64x64 via 4x4 16x16x32 MFMA tiles.
template <int K, int ACT>
__global__ __launch_bounds__(256) void k_gemm(const unsigned short* __restrict__ A,
                                              const unsigned short* __restrict__ W,
                                              unsigned short* __restrict__ Out,
                                              float* __restrict__ S1, float* __restrict__ S2,
                                              const float* __restrict__ cA,
                                              const float* __restrict__ cC) {
    __shared__ alignas(16) unsigned short As[128 * 64];
    __shared__ alignas(16) unsigned short Bs[128 * 64];
    __shared__ float sS1[128], sS2[128];

    int tid = threadIdx.x;
    int l0 = blockIdx.x * 128;
    int o0 = blockIdx.y * 128;
    int wave = tid >> 6, lane = tid & 63, quad = lane >> 4, lr = lane & 15;
    int wm = wave >> 1, wn = wave & 1;

    floatx4 zero4 = {0.f, 0.f, 0.f, 0.f};
    floatx4 acc[4][4];
#pragma unroll
    for (int mi = 0; mi < 4; ++mi)
#pragma unroll
        for (int ni = 0; ni < 4; ++ni) acc[mi][ni] = zero4;

    constexpr int KC = K / 64;
    for (int kc = 0; kc < KC; ++kc) {
        __syncthreads();
        // stage A and B tiles (128 x 64 bf16 each); XOR-swizzled 16B chunks
#pragma unroll
        for (int it = 0; it < 4; ++it) {
            int idx = it * 256 + tid;
            int row = idx >> 3, c8 = idx & 7;
            union { uint4 v; unsigned short u[8]; } va;
            va.v = *(const uint4*)(A + (size_t)(l0 + row) * K + kc * 64 + c8 * 8);
            if (ACT) {
                int kbase = kc * 64 + c8 * 8;
#pragma unroll
                for (int j = 0; j < 8; ++j) {
                    float f = bf2f(va.u[j]);
                    va.u[j] = f2bf(gelu_f(cA[kbase + j] * f + cC[kbase + j]));
                }
            }
            *(uint4*)&As[row * 64 + ((c8 ^ (row & 7)) << 3)] = va.v;

            uint4 vb = *(const uint4*)(W + (size_t)(o0 + row) * K + kc * 64 + c8 * 8);
            *(uint4*)&Bs[row * 64 + ((c8 ^ (row & 7)) << 3)] = vb;
        }
        __syncthreads();
#pragma unroll
        for (int ks8 = 0; ks8 < 2; ++ks8) {
            bf16x8 af[4], bfr[4];
#pragma unroll
            for (int mi = 0; mi < 4; ++mi) {
                int ra = wm * 64 + mi * 16 + lr;
                af[mi] = *(const bf16x8*)&As[ra * 64 + ((((ks8 << 2) + quad) ^ (ra & 7)) << 3)];
            }
#pragma unroll
            for (int ni = 0; ni < 4; ++ni) {
                int rb = wn * 64 + ni * 16 + lr;
                bfr[ni] = *(const bf16x8*)&Bs[rb * 64 + ((((ks8 << 2) + quad) ^ (rb & 7)) << 3)];
            }
#pragma unroll
            for (int mi = 0; mi < 4; ++mi)
#pragma unroll
                for (int ni = 0; ni < 4; ++ni)
                    acc[mi][ni] = __builtin_amdgcn_mfma_f32_16x16x32_bf16(af[mi], bfr[ni], acc[mi][ni], 0, 0, 0);
        }
    }

    // epilogue: write bf16 + per-channel partial sums (for BN stats)
    float p1[4] = {0, 0, 0, 0}, p2[4] = {0, 0, 0, 0};
#pragma unroll
    for (int mi = 0; mi < 4; ++mi) {
#pragma unroll
        for (int ni = 0; ni < 4; ++ni) {
#pragma unroll
            for (int r = 0; r < 4; ++r) {
                float v = acc[mi][ni][r];
                int row = l0 + wm * 64 + mi * 16 + quad * 4 + r;
                int col = o0 + wn * 64 + ni * 16 + lr;
                Out[(size_t)row * OC + col] = f2bf(v);
                p1[ni] += v;
                p2[ni] += v * v;
            }
        }
    }
    if (tid < 128) { sS1[tid] = 0.f; sS2[tid] = 0.f; }
    __syncthreads();
#pragma unroll
    for (int ni = 0; ni < 4; ++ni) {
        atomicAdd(&sS1[wn * 64 + ni * 16 + lr], p1[ni]);
        atomicAdd(&sS2[wn * 64 + ni * 16 + lr], p2[ni]);
    }
    __syncthreads();
    if (tid < 128) {
        atomicAdd(&S1[o0 + tid], sS1[tid]);
        atomicAdd(&S2[o0 + tid], sS2[tid]);
    }
}

// ---------------- BN coefficient finalize: a = g*rsqrt(var+eps), c = bt - mean*a ----------------
__global__ void k_finalize(const float* __restrict__ S1, const float* __restrict__ S2,
                           const void* __restrict__ g_, const void* __restrict__ bt_,
                           const int* __restrict__ dflag,
                           float* __restrict__ cA, float* __restrict__ cC) {
    int o = threadIdx.x;
    float m = S1[o] * (1.0f / (float)L);
    float var = S2[o] * (1.0f / (float)L) - m * m;
    float g, bt;
    if (*dflag) { g = ((const float*)g_)[o]; bt = ((const float*)bt_)[o]; }
    else { g = bf2f(((const unsigned short*)g_)[o]); bt = bf2f(((const unsigned short*)bt_)[o]); }
    float a = g * rsqrtf(var + BN_EPS);
    cA[o] = a;
    cC[o] = bt - m * a;
}

// ---------------- final: out = gelu( bn2(t2) + gelu(bn0(t0)) ); out dtype per dflag ----------------
__global__ __launch_bounds__(256) void k_final(const unsigned short* __restrict__ t0,
                                               const unsigned short* __restrict__ t2,
                                               const float* __restrict__ cA0, const float* __restrict__ cC0,
                                               const float* __restrict__ cA2, const float* __restrict__ cC2,
                                               const int* __restrict__ dflag,
                                               void* __restrict__ out_) {
    int idx = (blockIdx.x * 256 + threadIdx.x) * 8;
    int col = idx & (OC - 1);
    union { uint4 v; unsigned short u[8]; } v0, v2;
    v0.v = *(const uint4*)(t0 + idx);
    v2.v = *(const uint4*)(t2 + idx);
    float r[8];
#pragma unroll
    for (int j = 0; j < 8; ++j) {
        float x = gelu_f(cA0[col + j] * bf2f(v0.u[j]) + cC0[col + j]);
        float y = cA2[col + j] * bf2f(v2.u[j]) + cC2[col + j];
        r[j] = gelu_f(x + y);
    }
    if (*dflag) {
        float* o = (float*)out_ + idx;
        float4 lo = {r[0], r[1], r[2], r[3]};
        float4 hi = {r[4], r[5], r[6], r[7]};
        *(float4*)o = lo;
        *(float4*)(o + 4) = hi;
    } else {
        union { uint4 v; unsigned short u[8]; } vo;
#pragma unroll
        for (int j = 0; j < 8; ++j) vo.u[j] = f2bf(r[j]);
        *(uint4*)((unsigned short*)out_ + idx) = vo.v;
    }
}

extern "C" void kernel_launch(void* const* d_in, const int* in_sizes, int n_in,
                              void* d_out, int out_size, void* d_ws, size_t ws_size,
                              hipStream_t stream) {
    const void* xyz1    = d_in[0];
    const void* xyz2    = d_in[1];
    const void* points1 = d_in[2];
    const void* points2 = d_in[3];
    const void* W_fuse  = d_in[4];
    const void* g_fuse  = d_in[6];
    const void* bt_fuse = d_in[7];
    const void* W1      = d_in[8];
    const void* g1      = d_in[10];
    const void* bt1     = d_in[11];
    const void* W2      = d_in[12];
    const void* g2      = d_in[14];
    const void* bt2     = d_in[15];

    char* ws = (char*)d_ws;
    // ws layout: X (24MB, reused as t2) | t0 (16MB) | nn_idx | nn_w | stats+flag | Wbf x3.
    // t1 lives in d_out (scratch until k_final overwrites it).
    unsigned short* X  = (unsigned short*)ws;
    unsigned short* t0 = (unsigned short*)(ws + 25165824);
    unsigned short* t1 = (unsigned short*)d_out;   // 16.8 MB bf16 scratch; d_out >= 16.8 MB either dtype
    unsigned short* t2 = X;                        // X dead after GEMM1
    int*   nn_idx = (int*)(ws + 41943040);
    float* nn_w   = (float*)(ws + 42336256);
    float* stats  = (float*)(ws + 42729472);
    int*   dflag  = (int*)(ws + 42729472 + 3072 * 4);
    unsigned short* Wf_bf = (unsigned short*)(ws + 42745856);
    unsigned short* W1_bf = Wf_bf + 256 * KIN;
    unsigned short* W2_bf = W1_bf + 256 * OC;

    float *S1_0 = stats,        *S2_0 = stats + 256;
    float *S1_1 = stats + 512,  *S2_1 = stats + 768;
    float *S1_2 = stats + 1024, *S2_2 = stats + 1280;
    float *cA0 = stats + 1536, *cC0 = stats + 1792;
    float *cA1 = stats + 2048, *cC1 = stats + 2304;
    float *cA2 = stats + 2560, *cC2 = stats + 2816;

    k_probe<<<1, 64, 0, stream>>>((const unsigned int*)xyz1, dflag);
    k_zero<<<6, 256, 0, stream>>>(stats);
    k_prep_w<<<(256 * KIN + 255) / 256, 256, 0, stream>>>(W_fuse, Wf_bf, 256 * KIN, dflag);
    k_prep_w<<<(256 * OC + 255) / 256, 256, 0, stream>>>(W1, W1_bf, 256 * OC, dflag);
    k_prep_w<<<(256 * OC + 255) / 256, 256, 0, stream>>>(W2, W2_bf, 256 * OC, dflag);
    k_nn<<<128, 256, 0, stream>>>(xyz1, xyz2, dflag, nn_idx, nn_w);
    k_build_x<<<L / 4, 256, 0, stream>>>(points1, points2, dflag, nn_idx, nn_w, X);

    dim3 ggrid(L / 128, 2);
    k_gemm<KIN, 0><<<ggrid, 256, 0, stream>>>(X, Wf_bf, t0, S1_0, S2_0, nullptr, nullptr);
    k_finalize<<<1, 256, 0, stream>>>(S1_0, S2_0, g_fuse, bt_fuse, dflag, cA0, cC0);
    k_gemm<OC, 1><<<ggrid, 256, 0, stream>>>(t0, W1_bf, t1, S1_1, S2_1, cA0, cC0);
    k_finalize<<<1, 256, 0, stream>>>(S1_1, S2_1, g1, bt1, dflag, cA1, cC1);
    k_gemm<OC, 1><<<ggrid, 256, 0, stream>>>(t1, W2_bf, t2, S1_2, S2_2, cA1, cC1);
    k_finalize<<<1, 256, 0, stream>>>(S1_2, S2_2, g2, bt2, dflag, cA2, cC2);
    k_final<<<L * OC / (256 * 8), 256, 0, stream>>>(t0, t2, cA0, cC0, cA2, cC2, dflag, d_out);
}

// Round 5
// 245.806 us; speedup vs baseline: 1.4167x; 1.1353x over previous
//
#include <hip/hip_runtime.h>
#include <hip/hip_bf16.h>

// Problem constants
constexpr int Bb = 8, Nn = 4096, Ss = 1024;
constexpr int D1 = 128, D2 = 256, KIN = 384, OC = 256;
constexpr int L = Bb * Nn;             // 32768 rows
constexpr float BN_EPS = 1e-5f;

typedef __attribute__((ext_vector_type(4))) float floatx4;
typedef __attribute__((ext_vector_type(8))) __bf16 bf16x8;

#define DEV __device__ __forceinline__

DEV float bf2f(unsigned short u) {
    union { unsigned int i; float f; } v; v.i = ((unsigned int)u) << 16; return v.f;
}
DEV unsigned short f2bf(float f) {
    union { float f; unsigned int i; } v; v.f = f;
    unsigned int x = v.i;
    return (unsigned short)((x + 0x7FFFu + ((x >> 16) & 1u)) >> 16);  // RNE
}
// Fast tanh-form gelu: x*sigmoid(2u), u = sqrt(2/pi)*(x+0.044715x^3).
DEV float gelu_f(float x) {
    float u = x * (0.7978845608f + 0.0356774081f * x * x);
    float t = __expf(-2.0f * u);
    return x * __builtin_amdgcn_rcpf(1.0f + t);
}

// ---------------- dtype probe: low ushort of f32 words is mantissa junk ----------------
__global__ void k_probe(const unsigned int* __restrict__ w, int* __restrict__ flag) {
    if (threadIdx.x == 0 && blockIdx.x == 0) {
        int sane = 0;
        for (int i = 0; i < 64; ++i) {
            unsigned int lo = w[i] & 0xFFFFu;
            int e = (int)((lo >> 7) & 0xFF);
            if (e >= 100 && e <= 144) ++sane;
        }
        *flag = (sane >= 48) ? 0 : 1;   // 0 = bf16 inputs, 1 = f32 inputs
    }
}

// ---------------- zero stats accumulators ----------------
__global__ void k_zero(float* p) {
    int i = blockIdx.x * 256 + threadIdx.x;
    if (i < 6 * 256) p[i] = 0.0f;
}

// ---------------- weights -> bf16 (copy or convert) ----------------
__global__ void k_prep_w(const void* __restrict__ src, unsigned short* __restrict__ dst,
                         int n, const int* __restrict__ dflag) {
    int i = blockIdx.x * 256 + threadIdx.x;
    if (i >= n) return;
    if (*dflag) dst[i] = f2bf(((const float*)src)[i]);
    else        dst[i] = ((const unsigned short*)src)[i];
}

// Branchless merge of two sorted (asc) top-3 lists; pref=true -> ties keep "a" side.
DEV void merge3(float& d0, float& d1, float& d2, int& i0, int& i1, int& i2,
                float e0, float e1, float e2, int j0, int j1, int j2, bool pref) {
    float a0 = d0, a1 = d1, a2 = d2; int x0 = i0, x1 = i1, x2 = i2;
    float b0 = e0, b1 = e1;          int y0 = j0, y1 = j1;
    bool t = pref ? (a0 <= b0) : (a0 < b0);
    d0 = t ? a0 : b0; i0 = t ? x0 : y0;
    a0 = t ? a1 : a0; x0 = t ? x1 : x0;
    a1 = t ? a2 : a1; x1 = t ? x2 : x1;
    b0 = t ? b0 : b1; y0 = t ? y0 : y1;
    b1 = t ? b1 : e2; y1 = t ? y1 : j2;
    t = pref ? (a0 <= b0) : (a0 < b0);
    d1 = t ? a0 : b0; i1 = t ? x0 : y0;
    a0 = t ? a1 : a0; x0 = t ? x1 : x0;
    b0 = t ? b0 : b1; y0 = t ? y0 : y1;
    t = pref ? (a0 <= b0) : (a0 < b0);
    d2 = t ? a0 : b0; i2 = t ? x0 : y0;
}

// ---------------- 3-NN search + weights ----------------
// 8 lanes cooperate per query: part=tid&7 scans 128 of 1024 sources, then a
// 3-stage shfl_xor merge combines sorted top-3 lists. Grid: 1024 blocks x 256
// threads = 32 queries/block -> 4 blocks/CU (vs 0.5 before: was latency-bound
// at 5% occupancy, 1 wave/SIMD).
__global__ __launch_bounds__(256) void k_nn(const void* __restrict__ xyz1_,
                                            const void* __restrict__ xyz2_,
                                            const int* __restrict__ dflag,
                                            int* __restrict__ nn_idx, float* __restrict__ nn_w) {
    // 16B pad per 128-source region: part p's float4 reads land on bank group
    // 4p..4p+3 -> 8 parts cover all 32 banks, conflict-free.
    __shared__ alignas(16) float s4[Ss * 4 + 32];
    int tid = threadIdx.x;
    int b = (blockIdx.x * 32) >> 12;   // 32 queries/block, 4096 queries/batch
    bool isf = (*dflag != 0);

    if (isf) {
        const float* p2 = (const float*)xyz2_ + (size_t)b * Ss * 3;
        for (int i = tid; i < Ss * 3; i += 256) {
            int s = i / 3, k = i - s * 3;
            s4[s * 4 + k + ((s >> 7) << 2)] = p2[i];
        }
    } else {
        const unsigned short* p2 = (const unsigned short*)xyz2_ + (size_t)b * Ss * 3;
        for (int i = tid; i < Ss * 3; i += 256) {
            int s = i / 3, k = i - s * 3;
            s4[s * 4 + k + ((s >> 7) << 2)] = bf2f(p2[i]);
        }
    }
    __syncthreads();
    for (int s = tid; s < Ss; s += 256) {
        int a = s * 4 + ((s >> 7) << 2);
        float x = s4[a], y = s4[a + 1], z = s4[a + 2];
        s4[a + 3] = x * x + y * y + z * z;
    }
    __syncthreads();

    int part = tid & 7;
    int bn = blockIdx.x * 32 + (tid >> 3);
    float x1, y1, z1;
    if (isf) {
        const float* p1 = (const float*)xyz1_ + (size_t)bn * 3;
        x1 = p1[0]; y1 = p1[1]; z1 = p1[2];
    } else {
        const unsigned short* p1 = (const unsigned short*)xyz1_ + (size_t)bn * 3;
        x1 = bf2f(p1[0]); y1 = bf2f(p1[1]); z1 = bf2f(p1[2]);
    }
    float n1 = x1 * x1 + y1 * y1 + z1 * z1;

    float d0 = 3.4e38f, d1 = 3.4e38f, d2 = 3.4e38f;
    int i0 = 0, i1 = 0, i2 = 0;
    const float* sp = &s4[part * 516];  // part*128*4 + part*4
#pragma unroll 4
    for (int j = 0; j < 128; ++j) {
        float4 q = *(const float4*)(sp + j * 4);
        float d = n1 + q.w - 2.0f * (x1 * q.x + y1 * q.y + z1 * q.z);
        int s = part * 128 + j;
        bool c2 = d < d2, c1 = d < d1, c0 = d < d0;
        d2 = c1 ? d1 : (c2 ? d : d2); i2 = c1 ? i1 : (c2 ? s : i2);
        d1 = c0 ? d0 : (c1 ? d : d1); i1 = c0 ? i0 : (c1 ? s : i1);
        d0 = c0 ? d  : d0;            i0 = c0 ? s  : i0;
    }
    // merge the 8 parts' sorted top-3 (lanes 8p..8p+7 are one query, same wave)
#pragma unroll
    for (int m = 1; m <= 4; m <<= 1) {
        float e0 = __shfl_xor(d0, m, 64), e1 = __shfl_xor(d1, m, 64), e2 = __shfl_xor(d2, m, 64);
        int   j0 = __shfl_xor(i0, m, 64), j1 = __shfl_xor(i1, m, 64), j2 = __shfl_xor(i2, m, 64);
        bool pref = (part < (part ^ m));  // lower part = lower source indices wins ties
        merge3(d0, d1, d2, i0, i1, i2, e0, e1, e2, j0, j1, j2, pref);
    }
    if (part == 0) {
        float r0 = 1.0f / (d0 + 1e-8f), r1 = 1.0f / (d1 + 1e-8f), r2 = 1.0f / (d2 + 1e-8f);
        float rs = 1.0f / (r0 + r1 + r2);
        nn_idx[bn * 3 + 0] = i0; nn_idx[bn * 3 + 1] = i1; nn_idx[bn * 3 + 2] = i2;
        nn_w[bn * 3 + 0] = r0 * rs; nn_w[bn * 3 + 1] = r1 * rs; nn_w[bn * 3 + 2] = r2 * rs;
    }
}

// ---------------- build X = concat(points1, interp) as (L, 384) bf16 ----------------
// grid: 8192 blocks x 256 threads; 4 points/block, 64 lanes per point
__global__ __launch_bounds__(256) void k_build_x(const void* __restrict__ points1_,
                                                 const void* __restrict__ points2_,
                                                 const int* __restrict__ dflag,
                                                 const int* __restrict__ nn_idx,
                                                 const float* __restrict__ nn_w,
                                                 unsigned short* __restrict__ X) {
    int tid = threadIdx.x;
    int pt = blockIdx.x * 4 + (tid >> 6);
    int lane = tid & 63;
    int b = pt >> 12;  // / Nn
    bool isf = (*dflag != 0);

    int i0 = nn_idx[pt * 3], i1 = nn_idx[pt * 3 + 1], i2 = nn_idx[pt * 3 + 2];
    float w0 = nn_w[pt * 3], w1 = nn_w[pt * 3 + 1], w2 = nn_w[pt * 3 + 2];
    int c = lane * 4;  // 4 interp channels / lane

    if (isf) {
        const float* p1 = (const float*)points1_ + (size_t)pt * D1;
        float2 v = *(const float2*)(p1 + lane * 2);
        unsigned int packed = (unsigned int)f2bf(v.x) | ((unsigned int)f2bf(v.y) << 16);
        ((unsigned int*)(X + (size_t)pt * KIN))[lane] = packed;

        const float* base = (const float*)points2_;
        const float* r0 = base + ((size_t)(b * Ss + i0)) * D2 + c;
        const float* r1 = base + ((size_t)(b * Ss + i1)) * D2 + c;
        const float* r2 = base + ((size_t)(b * Ss + i2)) * D2 + c;
        float4 a0 = *(const float4*)r0;
        float4 a1 = *(const float4*)r1;
        float4 a2 = *(const float4*)r2;
        uint2 out;
        unsigned short* uo = (unsigned short*)&out;
        uo[0] = f2bf(w0 * a0.x + w1 * a1.x + w2 * a2.x);
        uo[1] = f2bf(w0 * a0.y + w1 * a1.y + w2 * a2.y);
        uo[2] = f2bf(w0 * a0.z + w1 * a1.z + w2 * a2.z);
        uo[3] = f2bf(w0 * a0.w + w1 * a1.w + w2 * a2.w);
        *(uint2*)(X + (size_t)pt * KIN + D1 + c) = out;
    } else {
        const unsigned short* p1 = (const unsigned short*)points1_;
        ((unsigned int*)(X + (size_t)pt * KIN))[lane] =
            ((const unsigned int*)(p1 + (size_t)pt * D1))[lane];

        const unsigned short* base = (const unsigned short*)points2_;
        const unsigned short* r0 = base + ((size_t)(b * Ss + i0)) * D2 + c;
        const unsigned short* r1 = base + ((size_t)(b * Ss + i1)) * D2 + c;
        const unsigned short* r2 = base + ((size_t)(b * Ss + i2)) * D2 + c;
        uint2 v0 = *(const uint2*)r0;
        uint2 v1 = *(const uint2*)r1;
        uint2 v2 = *(const uint2*)r2;
        const unsigned short* u0 = (const unsigned short*)&v0;
        const unsigned short* u1 = (const unsigned short*)&v1;
        const unsigned short* u2 = (const unsigned short*)&v2;
        uint2 out;
        unsigned short* uo = (unsigned short*)&out;
#pragma unroll
        for (int j = 0; j < 4; ++j)
            uo[j] = f2bf(w0 * bf2f(u0[j]) + w1 * bf2f(u1[j]) + w2 * bf2f(u2[j]));
        *(uint2*)(X + (size_t)pt * KIN + D1 + c) = out;
    }
}

// ---------------- GEMM: C[l][o] = sum_c act(A[l][c]) * W[o][c], + channel stats ----------------
// A: (L,K) bf16 row-major; W: (256,K) bf16 row-major; Out: (L,256) bf16.
// ACT: apply gelu(cA[c]*x + cC[c]) to A during staging.
// grid: (L/128, 2); 256 threads = 4 waves (2x2), each wave 64x64 via 4x4 16x16x32 MFMA tiles.
template <int K, int ACT>
__global__ __launch_bounds__(256) void k_gemm(const unsigned short* __restrict__ A,
                                              const unsigned short* __restrict__ W,
                                              unsigned short* __restrict__ Out,
                                              float* __restrict__ S1, float* __restrict__ S2,
                                              const float* __restrict__ cA,
                                              const float* __restrict__ cC) {
    __shared__ alignas(16) unsigned short As[128 * 64];
    __shared__ alignas(16) unsigned short Bs[128 * 64];
    __shared__ float sS1[128], sS2[128];

    int tid = threadIdx.x;
    int l0 = blockIdx.x * 128;
    int o0 = blockIdx.y * 128;
    int wave = tid >> 6, lane = tid & 63, quad = lane >> 4, lr = lane & 15;
    int wm = wave >> 1, wn = wave & 1;

    floatx4 zero4 = {0.f, 0.f, 0.f, 0.f};
    floatx4 acc[4][4];
#pragma unroll
    for (int mi = 0; mi < 4; ++mi)
#pragma unroll
        for (int ni = 0; ni < 4; ++ni) acc[mi][ni] = zero4;

    constexpr int KC = K / 64;
    for (int kc = 0; kc < KC; ++kc) {
        __syncthreads();
        // stage A and B tiles (128 x 64 bf16 each); XOR-swizzled 16B chunks
#pragma unroll
        for (int it = 0; it < 4; ++it) {
            int idx = it * 256 + tid;
            int row = idx >> 3, c8 = idx & 7;
            union { uint4 v; unsigned short u[8]; } va;
            va.v = *(const uint4*)(A + (size_t)(l0 + row) * K + kc * 64 + c8 * 8);
            if (ACT) {
                int kbase = kc * 64 + c8 * 8;
#pragma unroll
                for (int j = 0; j < 8; ++j) {
                    float f = bf2f(va.u[j]);
                    va.u[j] = f2bf(gelu_f(cA[kbase + j] * f + cC[kbase + j]));
                }
            }
            *(uint4*)&As[row * 64 + ((c8 ^ (row & 7)) << 3)] = va.v;

            uint4 vb = *(const uint4*)(W + (size_t)(o0 + row) * K + kc * 64 + c8 * 8);
            *(uint4*)&Bs[row * 64 + ((c8 ^ (row & 7)) << 3)] = vb;
        }
        __syncthreads();
#pragma unroll
        for (int ks8 = 0; ks8 < 2; ++ks8) {
            bf16x8 af[4], bfr[4];
#pragma unroll
            for (int mi = 0; mi < 4; ++mi) {
                int ra = wm * 64 + mi * 16 + lr;
                af[mi] = *(const bf16x8*)&As[ra * 64 + ((((ks8 << 2) + quad) ^ (ra & 7)) << 3)];
            }
#pragma unroll
            for (int ni = 0; ni < 4; ++ni) {
                int rb = wn * 64 + ni * 16 + lr;
                bfr[ni] = *(const bf16x8*)&Bs[rb * 64 + ((((ks8 << 2) + quad) ^ (rb & 7)) << 3)];
            }
#pragma unroll
            for (int mi = 0; mi < 4; ++mi)
#pragma unroll
                for (int ni = 0; ni < 4; ++ni)
                    acc[mi][ni] = __builtin_amdgcn_mfma_f32_16x16x32_bf16(af[mi], bfr[ni], acc[mi][ni], 0, 0, 0);
        }
    }

    // epilogue: write bf16 + per-channel partial sums (for BN stats)
    float p1[4] = {0, 0, 0, 0}, p2[4] = {0, 0, 0, 0};
#pragma unroll
    for (int mi = 0; mi < 4; ++mi) {
#pragma unroll
        for (int ni = 0; ni < 4; ++ni) {
#pragma unroll
            for (int r = 0; r < 4; ++r) {
                float v = acc[mi][ni][r];
                int row = l0 + wm * 64 + mi * 16 + quad * 4 + r;
                int col = o0 + wn * 64 + ni * 16 + lr;
                Out[(size_t)row * OC + col] = f2bf(v);
                p1[ni] += v;
                p2[ni] += v * v;
            }
        }
    }
    if (tid < 128) { sS1[tid] = 0.f; sS2[tid] = 0.f; }
    __syncthreads();
#pragma unroll
    for (int ni = 0; ni < 4; ++ni) {
        atomicAdd(&sS1[wn * 64 + ni * 16 + lr], p1[ni]);
        atomicAdd(&sS2[wn * 64 + ni * 16 + lr], p2[ni]);
    }
    __syncthreads();
    if (tid < 128) {
        atomicAdd(&S1[o0 + tid], sS1[tid]);
        atomicAdd(&S2[o0 + tid], sS2[tid]);
    }
}

// ---------------- BN coefficient finalize: a = g*rsqrt(var+eps), c = bt - mean*a ----------------
__global__ void k_finalize(const float* __restrict__ S1, const float* __restrict__ S2,
                           const void* __restrict__ g_, const void* __restrict__ bt_,
                           const int* __restrict__ dflag,
                           float* __restrict__ cA, float* __restrict__ cC) {
    int o = threadIdx.x;
    float m = S1[o] * (1.0f / (float)L);
    float var = S2[o] * (1.0f / (float)L) - m * m;
    float g, bt;
    if (*dflag) { g = ((const float*)g_)[o]; bt = ((const float*)bt_)[o]; }
    else { g = bf2f(((const unsigned short*)g_)[o]); bt = bf2f(((const unsigned short*)bt_)[o]); }
    float a = g * rsqrtf(var + BN_EPS);
    cA[o] = a;
    cC[o] = bt - m * a;
}

// ---------------- final: out = gelu( bn2(t2) + gelu(bn0(t0)) ); out dtype per dflag ----------------
__global__ __launch_bounds__(256) void k_final(const unsigned short* __restrict__ t0,
                                               const unsigned short* __restrict__ t2,
                                               const float* __restrict__ cA0, const float* __restrict__ cC0,
                                               const float* __restrict__ cA2, const float* __restrict__ cC2,
                                               const int* __restrict__ dflag,
                                               void* __restrict__ out_) {
    int idx = (blockIdx.x * 256 + threadIdx.x) * 8;
    int col = idx & (OC - 1);
    union { uint4 v; unsigned short u[8]; } v0, v2;
    v0.v = *(const uint4*)(t0 + idx);
    v2.v = *(const uint4*)(t2 + idx);
    float r[8];
#pragma unroll
    for (int j = 0; j < 8; ++j) {
        float x = gelu_f(cA0[col + j] * bf2f(v0.u[j]) + cC0[col + j]);
        float y = cA2[col + j] * bf2f(v2.u[j]) + cC2[col + j];
        r[j] = gelu_f(x + y);
    }
    if (*dflag) {
        float* o = (float*)out_ + idx;
        float4 lo = {r[0], r[1], r[2], r[3]};
        float4 hi = {r[4], r[5], r[6], r[7]};
        *(float4*)o = lo;
        *(float4*)(o + 4) = hi;
    } else {
        union { uint4 v; unsigned short u[8]; } vo;
#pragma unroll
        for (int j = 0; j < 8; ++j) vo.u[j] = f2bf(r[j]);
        *(uint4*)((unsigned short*)out_ + idx) = vo.v;
    }
}

extern "C" void kernel_launch(void* const* d_in, const int* in_sizes, int n_in,
                              void* d_out, int out_size, void* d_ws, size_t ws_size,
                              hipStream_t stream) {
    const void* xyz1    = d_in[0];
    const void* xyz2    = d_in[1];
    const void* points1 = d_in[2];
    const void* points2 = d_in[3];
    const void* W_fuse  = d_in[4];
    const void* g_fuse  = d_in[6];
    const void* bt_fuse = d_in[7];
    const void* W1      = d_in[8];
    const void* g1      = d_in[10];
    const void* bt1     = d_in[11];
    const void* W2      = d_in[12];
    const void* g2      = d_in[14];
    const void* bt2     = d_in[15];

    char* ws = (char*)d_ws;
    // ws layout: X (24MB, reused as t2) | t0 (16MB) | nn_idx | nn_w | stats+flag | Wbf x3.
    // t1 lives in d_out (scratch until k_final overwrites it).
    unsigned short* X  = (unsigned short*)ws;
    unsigned short* t0 = (unsigned short*)(ws + 25165824);
    unsigned short* t1 = (unsigned short*)d_out;   // 16.8 MB bf16 scratch; d_out >= 16.8 MB either dtype
    unsigned short* t2 = X;                        // X dead after GEMM1
    int*   nn_idx = (int*)(ws + 41943040);
    float* nn_w   = (float*)(ws + 42336256);
    float* stats  = (float*)(ws + 42729472);
    int*   dflag  = (int*)(ws + 42729472 + 3072 * 4);
    unsigned short* Wf_bf = (unsigned short*)(ws + 42745856);
    unsigned short* W1_bf = Wf_bf + 256 * KIN;
    unsigned short* W2_bf = W1_bf + 256 * OC;

    float *S1_0 = stats,        *S2_0 = stats + 256;
    float *S1_1 = stats + 512,  *S2_1 = stats + 768;
    float *S1_2 = stats + 1024, *S2_2 = stats + 1280;
    float *cA0 = stats + 1536, *cC0 = stats + 1792;
    float *cA1 = stats + 2048, *cC1 = stats + 2304;
    float *cA2 = stats + 2560, *cC2 = stats + 2816;

    k_probe<<<1, 64, 0, stream>>>((const unsigned int*)xyz1, dflag);
    k_zero<<<6, 256, 0, stream>>>(stats);
    k_prep_w<<<(256 * KIN + 255) / 256, 256, 0, stream>>>(W_fuse, Wf_bf, 256 * KIN, dflag);
    k_prep_w<<<(256 * OC + 255) / 256, 256, 0, stream>>>(W1, W1_bf, 256 * OC, dflag);
    k_prep_w<<<(256 * OC + 255) / 256, 256, 0, stream>>>(W2, W2_bf, 256 * OC, dflag);
    k_nn<<<L / 32, 256, 0, stream>>>(xyz1, xyz2, dflag, nn_idx, nn_w);
    k_build_x<<<L / 4, 256, 0, stream>>>(points1, points2, dflag, nn_idx, nn_w, X);

    dim3 ggrid(L / 128, 2);
    k_gemm<KIN, 0><<<ggrid, 256, 0, stream>>>(X, Wf_bf, t0, S1_0, S2_0, nullptr, nullptr);
    k_finalize<<<1, 256, 0, stream>>>(S1_0, S2_0, g_fuse, bt_fuse, dflag, cA0, cC0);
    k_gemm<OC, 1><<<ggrid, 256, 0, stream>>>(t0, W1_bf, t1, S1_1, S2_1, cA0, cC0);
    k_finalize<<<1, 256, 0, stream>>>(S1_1, S2_1, g1, bt1, dflag, cA1, cC1);
    k_gemm<OC, 1><<<ggrid, 256, 0, stream>>>(t1, W2_bf, t2, S1_2, S2_2, cA1, cC1);
    k_finalize<<<1, 256, 0, stream>>>(S1_2, S2_2, g2, bt2, dflag, cA2, cC2);
    k_final<<<L * OC / (256 * 8), 256, 0, stream>>>(t0, t2, cA0, cC0, cA2, cC2, dflag, d_out);
}